// Round 1
// baseline (523.549 us; speedup 1.0000x reference)
//
#include <hip/hip_runtime.h>
#include <stdint.h>

typedef unsigned short u16;
typedef __attribute__((ext_vector_type(4))) float f32x4;
typedef __attribute__((ext_vector_type(8))) short bfrag;

static __device__ __forceinline__ u16 f2bf(float f) {
  union { float f; uint32_t u; } v; v.f = f;
  return (u16)((v.u + 0x7fffu + ((v.u >> 16) & 1u)) >> 16);
}

// ---------------- pack Wq/Wk/Wv: [16][1024][64] f32 -> [1024][1024] bf16
// out[h*64+e][k] = W[h][k][e]
__global__ __launch_bounds__(256) void pack_w_hde(const float* __restrict__ W,
                                                  u16* __restrict__ Wt) {
  __shared__ float tile[64][65];
  const int h = blockIdx.y, k0 = blockIdx.x * 64;
  const int tid = threadIdx.x;
#pragma unroll
  for (int j = 0; j < 4; ++j) {
    int idx = tid + j * 256;
    int rr = idx >> 4, c4 = (idx & 15) * 4;
    const float4 v = *(const float4*)(W + (size_t)h * 65536 + (size_t)(k0 + rr) * 64 + c4);
    tile[rr][c4 + 0] = v.x; tile[rr][c4 + 1] = v.y;
    tile[rr][c4 + 2] = v.z; tile[rr][c4 + 3] = v.w;
  }
  __syncthreads();
#pragma unroll
  for (int j = 0; j < 4; ++j) {
    int idx = tid + j * 256;
    int ee = idx >> 4, c4 = (idx & 15) * 4;
    uint2 u;
    u.x = f2bf(tile[c4 + 0][ee]) | ((uint32_t)f2bf(tile[c4 + 1][ee]) << 16);
    u.y = f2bf(tile[c4 + 2][ee]) | ((uint32_t)f2bf(tile[c4 + 3][ee]) << 16);
    *(uint2*)(Wt + (size_t)(h * 64 + ee) * 1024 + k0 + c4) = u;
  }
}

// ---------------- transpose Wo: [1024][1024] f32 -> bf16, out[n][k] = Wo[k][n]
__global__ __launch_bounds__(256) void transpose_w(const float* __restrict__ W,
                                                   u16* __restrict__ Wt) {
  __shared__ float tile[64][65];
  const int k0 = blockIdx.x * 64, n0 = blockIdx.y * 64;
  const int tid = threadIdx.x;
#pragma unroll
  for (int j = 0; j < 4; ++j) {
    int idx = tid + j * 256;
    int rr = idx >> 4, c4 = (idx & 15) * 4;
    const float4 v = *(const float4*)(W + (size_t)(k0 + rr) * 1024 + n0 + c4);
    tile[rr][c4 + 0] = v.x; tile[rr][c4 + 1] = v.y;
    tile[rr][c4 + 2] = v.z; tile[rr][c4 + 3] = v.w;
  }
  __syncthreads();
#pragma unroll
  for (int j = 0; j < 4; ++j) {
    int idx = tid + j * 256;
    int ee = idx >> 4, c4 = (idx & 15) * 4;
    uint2 u;
    u.x = f2bf(tile[c4 + 0][ee]) | ((uint32_t)f2bf(tile[c4 + 1][ee]) << 16);
    u.y = f2bf(tile[c4 + 2][ee]) | ((uint32_t)f2bf(tile[c4 + 3][ee]) << 16);
    *(uint2*)(Wt + (size_t)(n0 + ee) * 1024 + k0 + c4) = u;
  }
}

// ---------------- GEMM: C[M=8192, N=1024] = A[M,1024] * Bt[n][k]^T + bias[n]
// A is f32 (converted to bf16 in staging) or bf16. Bt bf16 [1024][1024] = B^T.
// 128x128 tile, 4 waves, 16x16x32 MFMA, 4x4 acc/wave.
template <bool A_F32, bool OUT_F32>
__global__ __launch_bounds__(256) void gemm128(const void* __restrict__ Av,
                                               const u16* __restrict__ Bt,
                                               const float* __restrict__ bias,
                                               void* __restrict__ Cv) {
  __shared__ u16 As[128][40];
  __shared__ u16 Bs[128][40];
  const int tid = threadIdx.x;
  const int mb = blockIdx.y, nb = blockIdx.x;
  const int wid = tid >> 6, lane = tid & 63;
  const int wr = wid >> 1, wc = wid & 1;
  const int g = lane >> 4, l15 = lane & 15;
  const int r0 = tid >> 2;
  const int c0 = (tid & 3) * 8;
  f32x4 acc[4][4] = {};

  for (int kk = 0; kk < 32; ++kk) {
    const int k0 = kk * 32;
    __syncthreads();
    // stage A
#pragma unroll
    for (int c = 0; c < 2; ++c) {
      const int row = r0 + c * 64;
      if (A_F32) {
        const float* p = (const float*)Av + (size_t)(mb * 128 + row) * 1024 + k0 + c0;
        const float4 f0 = *(const float4*)p;
        const float4 f1 = *(const float4*)(p + 4);
        uint4 u;
        u.x = f2bf(f0.x) | ((uint32_t)f2bf(f0.y) << 16);
        u.y = f2bf(f0.z) | ((uint32_t)f2bf(f0.w) << 16);
        u.z = f2bf(f1.x) | ((uint32_t)f2bf(f1.y) << 16);
        u.w = f2bf(f1.z) | ((uint32_t)f2bf(f1.w) << 16);
        *(uint4*)&As[row][c0] = u;
      } else {
        *(uint4*)&As[row][c0] =
            *(const uint4*)((const u16*)Av + (size_t)(mb * 128 + row) * 1024 + k0 + c0);
      }
      // stage B
      *(uint4*)&Bs[row][c0] =
          *(const uint4*)(Bt + (size_t)(nb * 128 + row) * 1024 + k0 + c0);
    }
    __syncthreads();
    bfrag a[4], b[4];
#pragma unroll
    for (int m = 0; m < 4; ++m)
      a[m] = __builtin_bit_cast(bfrag, *(const uint4*)&As[wr * 64 + m * 16 + l15][g * 8]);
#pragma unroll
    for (int n = 0; n < 4; ++n)
      b[n] = __builtin_bit_cast(bfrag, *(const uint4*)&Bs[wc * 64 + n * 16 + l15][g * 8]);
#pragma unroll
    for (int m = 0; m < 4; ++m)
#pragma unroll
      for (int n = 0; n < 4; ++n)
        acc[m][n] = __builtin_amdgcn_mfma_f32_16x16x32_bf16(a[m], b[n], acc[m][n], 0, 0, 0);
  }

  // epilogue
#pragma unroll
  for (int m = 0; m < 4; ++m) {
#pragma unroll
    for (int n = 0; n < 4; ++n) {
      const int row = mb * 128 + wr * 64 + m * 16 + g * 4;
      const int col = nb * 128 + wc * 64 + n * 16 + l15;
      const float bc = bias[col];
#pragma unroll
      for (int r = 0; r < 4; ++r) {
        const float v = acc[m][n][r] + bc;
        if (OUT_F32)
          ((float*)Cv)[(size_t)(row + r) * 1024 + col] = v;
        else
          ((u16*)Cv)[(size_t)(row + r) * 1024 + col] = f2bf(v);
      }
    }
  }
}

// ---------------- fused causal flash attention
// Q,K,V bf16 [B*S, 1024] (col = h*64+e). O bf16 same layout.
// Block: 8 waves x 16 q-rows = 128 q-rows per block. kv steps of 32.
__global__ __launch_bounds__(512) void attn_fused(const u16* __restrict__ Qb,
                                                  const u16* __restrict__ Kb,
                                                  const u16* __restrict__ Vb,
                                                  u16* __restrict__ Ob) {
  __shared__ u16 Ks[32][72];        // [kv][e(64) padded]
  __shared__ u16 Vt[64][40];        // [e][kv(32) padded]
  __shared__ u16 Plds[8][16][40];   // per-wave [q16][kv32 padded]
  const int tid = threadIdx.x;
  const int wid = tid >> 6, lane = tid & 63;
  const int g = lane >> 4, l15 = lane & 15;
  const int b = blockIdx.z, h = blockIdx.y;
  const int qb = blockIdx.x * 128;
  const int q0 = qb + wid * 16;
  const size_t baserow = (size_t)b * 2048;

  // Q fragments (row = l15, k = e = g*8+j, two k-halves)
  const u16* qp = Qb + (baserow + q0 + l15) * 1024 + h * 64 + g * 8;
  const bfrag qa0 = __builtin_bit_cast(bfrag, *(const uint4*)qp);
  const bfrag qa1 = __builtin_bit_cast(bfrag, *(const uint4*)(qp + 32));

  f32x4 acc[4] = {};
  float M[4], L[4];
#pragma unroll
  for (int r = 0; r < 4; ++r) { M[r] = -1e30f; L[r] = 0.f; }

  const int vrow = tid >> 4;        // 0..31 kv row for staging
  const int ve4 = (tid & 15) * 4;   // e offset for staging
  const int nsteps = (qb + 128) >> 5;

  for (int s = 0; s < nsteps; ++s) {
    const int kv0 = s * 32;
    __syncthreads();
    {
      const size_t grow = (baserow + kv0 + vrow) * 1024 + h * 64 + ve4;
      *(uint2*)&Ks[vrow][ve4] = *(const uint2*)(Kb + grow);
      const uint2 vv = *(const uint2*)(Vb + grow);
      u16 tmp[4];
      *(uint2*)tmp = vv;
#pragma unroll
      for (int i = 0; i < 4; ++i) Vt[ve4 + i][vrow] = tmp[i];
    }
    __syncthreads();

    // QK^T for two 16-col kv tiles
    f32x4 sc[2];
#pragma unroll
    for (int t = 0; t < 2; ++t) {
      const bfrag kb0 = __builtin_bit_cast(bfrag, *(const uint4*)&Ks[t * 16 + l15][g * 8]);
      const bfrag kb1 = __builtin_bit_cast(bfrag, *(const uint4*)&Ks[t * 16 + l15][32 + g * 8]);
      f32x4 z = {0.f, 0.f, 0.f, 0.f};
      z = __builtin_amdgcn_mfma_f32_16x16x32_bf16(qa0, kb0, z, 0, 0, 0);
      z = __builtin_amdgcn_mfma_f32_16x16x32_bf16(qa1, kb1, z, 0, 0, 0);
#pragma unroll
      for (int r = 0; r < 4; ++r) {
        const int qg = q0 + g * 4 + r;
        const int kvg = kv0 + t * 16 + l15;
        z[r] = (kvg <= qg) ? z[r] * 0.125f : -1e30f;
      }
      sc[t] = z;
    }

    // online softmax
    float mt[4];
#pragma unroll
    for (int r = 0; r < 4; ++r) mt[r] = fmaxf(sc[0][r], sc[1][r]);
#pragma unroll
    for (int off = 1; off < 16; off <<= 1)
#pragma unroll
      for (int r = 0; r < 4; ++r) mt[r] = fmaxf(mt[r], __shfl_xor(mt[r], off));
    float cf[4], rs[4];
#pragma unroll
    for (int r = 0; r < 4; ++r) {
      const float Mn = fmaxf(M[r], mt[r]);
      cf[r] = __expf(M[r] - Mn);
      M[r] = Mn;
      sc[0][r] = __expf(sc[0][r] - Mn);
      sc[1][r] = __expf(sc[1][r] - Mn);
      rs[r] = sc[0][r] + sc[1][r];
    }
#pragma unroll
    for (int off = 1; off < 16; off <<= 1)
#pragma unroll
      for (int r = 0; r < 4; ++r) rs[r] += __shfl_xor(rs[r], off);
#pragma unroll
    for (int r = 0; r < 4; ++r) L[r] = L[r] * cf[r] + rs[r];
#pragma unroll
    for (int et = 0; et < 4; ++et)
#pragma unroll
      for (int r = 0; r < 4; ++r) acc[et][r] *= cf[r];

    // P (C-layout) -> LDS -> A-operand layout
#pragma unroll
    for (int t = 0; t < 2; ++t)
#pragma unroll
      for (int r = 0; r < 4; ++r)
        Plds[wid][g * 4 + r][t * 16 + l15] = f2bf(sc[t][r]);
    const bfrag pa = __builtin_bit_cast(bfrag, *(const uint4*)&Plds[wid][l15][g * 8]);
#pragma unroll
    for (int et = 0; et < 4; ++et) {
      const bfrag vb = __builtin_bit_cast(bfrag, *(const uint4*)&Vt[et * 16 + l15][g * 8]);
      acc[et] = __builtin_amdgcn_mfma_f32_16x16x32_bf16(pa, vb, acc[et], 0, 0, 0);
    }
  }

  // normalize + store
  float inv[4];
#pragma unroll
  for (int r = 0; r < 4; ++r) inv[r] = 1.f / L[r];
#pragma unroll
  for (int et = 0; et < 4; ++et)
#pragma unroll
    for (int r = 0; r < 4; ++r)
      Ob[(baserow + q0 + g * 4 + r) * 1024 + h * 64 + et * 16 + l15] =
          f2bf(acc[et][r] * inv[r]);
}

extern "C" void kernel_launch(void* const* d_in, const int* in_sizes, int n_in,
                              void* d_out, int out_size, void* d_ws, size_t ws_size,
                              hipStream_t stream) {
  const float* keys    = (const float*)d_in[0];
  const float* queries = (const float*)d_in[1];
  const float* values  = (const float*)d_in[2];
  const float* Wq = (const float*)d_in[3];
  const float* bq = (const float*)d_in[4];
  const float* Wk = (const float*)d_in[5];
  const float* bk = (const float*)d_in[6];
  const float* Wv = (const float*)d_in[7];
  const float* bv = (const float*)d_in[8];
  const float* Wo = (const float*)d_in[9];
  const float* bo = (const float*)d_in[10];
  float* out = (float*)d_out;

  char* ws = (char*)d_ws;
  const size_t MB2 = 1u << 21, MB16 = 1u << 24;
  u16* Wqt = (u16*)(ws + 0 * MB2);
  u16* Wkt = (u16*)(ws + 1 * MB2);
  u16* Wvt = (u16*)(ws + 2 * MB2);
  u16* Wot = (u16*)(ws + 3 * MB2);
  u16* Qb  = (u16*)(ws + 4 * MB2 + 0 * MB16);
  u16* Kb  = (u16*)(ws + 4 * MB2 + 1 * MB16);
  u16* Vb  = (u16*)(ws + 4 * MB2 + 2 * MB16);
  u16* Ob  = (u16*)(ws + 4 * MB2 + 3 * MB16);

  const dim3 pg(16, 16);
  pack_w_hde<<<pg, 256, 0, stream>>>(Wq, Wqt);
  pack_w_hde<<<pg, 256, 0, stream>>>(Wk, Wkt);
  pack_w_hde<<<pg, 256, 0, stream>>>(Wv, Wvt);
  transpose_w<<<pg, 256, 0, stream>>>(Wo, Wot);

  const dim3 gg(8, 64);  // (N/128, M/128)
  gemm128<true, false><<<gg, 256, 0, stream>>>(queries, Wqt, bq, Qb);
  gemm128<true, false><<<gg, 256, 0, stream>>>(keys,    Wkt, bk, Kb);
  gemm128<true, false><<<gg, 256, 0, stream>>>(values,  Wvt, bv, Vb);

  attn_fused<<<dim3(16, 16, 4), 512, 0, stream>>>(Qb, Kb, Vb, Ob);

  gemm128<false, true><<<gg, 256, 0, stream>>>(Ob, Wot, bo, out);
}

// Round 2
// 397.549 us; speedup vs baseline: 1.3169x; 1.3169x over previous
//
#include <hip/hip_runtime.h>
#include <stdint.h>

typedef unsigned short u16;
typedef __attribute__((ext_vector_type(4))) float f32x4;
typedef __attribute__((ext_vector_type(8))) short bfrag;

static __device__ __forceinline__ u16 f2bf(float f) {  // RNE
  union { float f; uint32_t u; } v; v.f = f;
  return (u16)((v.u + 0x7fffu + ((v.u >> 16) & 1u)) >> 16);
}
static __device__ __forceinline__ u16 f2bf_ru(float f) {  // round-half-up, 2 ops
  union { float f; uint32_t u; } v; v.f = f;
  return (u16)((v.u + 0x8000u) >> 16);
}
// pack two f32 -> packed bf16x2 (round-half-up) in one v_perm
static __device__ __forceinline__ uint32_t pk2bf(float lo, float hi) {
  union { float f; uint32_t u; } a, b; a.f = lo; b.f = hi;
  return __builtin_amdgcn_perm(b.u + 0x8000u, a.u + 0x8000u, 0x07060302u);
}

#define GLOAD16(gp, lp)                                              \
  __builtin_amdgcn_global_load_lds(                                  \
      (const __attribute__((address_space(1))) uint32_t*)(gp),       \
      (__attribute__((address_space(3))) uint32_t*)(lp), 16, 0, 0)

// ---------------- pack Wq/Wk/Wv: [16][1024][64] f32 -> [1024][1024] bf16
// out[h*64+e][k] = W[h][k][e]
__global__ __launch_bounds__(256) void pack_w_hde(const float* __restrict__ W,
                                                  u16* __restrict__ Wt) {
  __shared__ float tile[64][65];
  const int h = blockIdx.y, k0 = blockIdx.x * 64;
  const int tid = threadIdx.x;
#pragma unroll
  for (int j = 0; j < 4; ++j) {
    int idx = tid + j * 256;
    int rr = idx >> 4, c4 = (idx & 15) * 4;
    const float4 v = *(const float4*)(W + (size_t)h * 65536 + (size_t)(k0 + rr) * 64 + c4);
    tile[rr][c4 + 0] = v.x; tile[rr][c4 + 1] = v.y;
    tile[rr][c4 + 2] = v.z; tile[rr][c4 + 3] = v.w;
  }
  __syncthreads();
#pragma unroll
  for (int j = 0; j < 4; ++j) {
    int idx = tid + j * 256;
    int ee = idx >> 4, c4 = (idx & 15) * 4;
    uint2 u;
    u.x = f2bf(tile[c4 + 0][ee]) | ((uint32_t)f2bf(tile[c4 + 1][ee]) << 16);
    u.y = f2bf(tile[c4 + 2][ee]) | ((uint32_t)f2bf(tile[c4 + 3][ee]) << 16);
    *(uint2*)(Wt + (size_t)(h * 64 + ee) * 1024 + k0 + c4) = u;
  }
}

// ---------------- transpose Wo: [1024][1024] f32 -> bf16, out[n][k] = Wo[k][n]
__global__ __launch_bounds__(256) void transpose_w(const float* __restrict__ W,
                                                   u16* __restrict__ Wt) {
  __shared__ float tile[64][65];
  const int k0 = blockIdx.x * 64, n0 = blockIdx.y * 64;
  const int tid = threadIdx.x;
#pragma unroll
  for (int j = 0; j < 4; ++j) {
    int idx = tid + j * 256;
    int rr = idx >> 4, c4 = (idx & 15) * 4;
    const float4 v = *(const float4*)(W + (size_t)(k0 + rr) * 1024 + n0 + c4);
    tile[rr][c4 + 0] = v.x; tile[rr][c4 + 1] = v.y;
    tile[rr][c4 + 2] = v.z; tile[rr][c4 + 3] = v.w;
  }
  __syncthreads();
#pragma unroll
  for (int j = 0; j < 4; ++j) {
    int idx = tid + j * 256;
    int ee = idx >> 4, c4 = (idx & 15) * 4;
    uint2 u;
    u.x = f2bf(tile[c4 + 0][ee]) | ((uint32_t)f2bf(tile[c4 + 1][ee]) << 16);
    u.y = f2bf(tile[c4 + 2][ee]) | ((uint32_t)f2bf(tile[c4 + 3][ee]) << 16);
    *(uint2*)(Wt + (size_t)(n0 + ee) * 1024 + k0 + c4) = u;
  }
}

// ---------------- GEMM: C[M=8192,N=1024] = A[M,1024]*Bt[n][k]^T + bias[n]
// B (and A when bf16) staged via global_load_lds width 16 into linear LDS.
// A f32 staged via reg-convert into padded LDS (stride 40).
// OUT_VT: write C transposed per (b,h): Cv[((b*16+h)*64+e)*2048 + s] (bf16)
template <bool A_F32, bool OUT_F32, bool OUT_VT>
__global__ __launch_bounds__(256) void gemm128(const void* __restrict__ Av,
                                               const u16* __restrict__ Bt,
                                               const float* __restrict__ bias,
                                               void* __restrict__ Cv) {
  constexpr int AST = A_F32 ? 40 : 32;
  __shared__ u16 As[128 * AST];
  __shared__ u16 Bs[128 * 32];
  const int tid = threadIdx.x;
  const int mb = blockIdx.y, nb = blockIdx.x;
  const int wid = tid >> 6, lane = tid & 63;
  const int wr = wid >> 1, wc = wid & 1;
  const int g = lane >> 4, l15 = lane & 15;
  f32x4 acc[4][4] = {};

  // global_load_lds addressing: wave wid stages chunks {2*wid, 2*wid+1};
  // chunk c = rows c*16..c*16+15, lane l -> row c*16 + (l>>2), col (l&3)*8.
  const u16* Bg = Bt + (size_t)(nb * 128 + 2 * wid * 16 + (lane >> 2)) * 1024 + (lane & 3) * 8;
  const u16* Ag16 = (const u16*)Av + (size_t)(mb * 128 + 2 * wid * 16 + (lane >> 2)) * 1024 + (lane & 3) * 8;
  const float* Af = (const float*)Av + (size_t)(mb * 128 + (tid >> 2)) * 1024 + (tid & 3) * 8;
  u16* AsB = &As[2 * wid * 512];
  u16* BsB = &Bs[2 * wid * 512];
  const int arow = tid >> 2, ac8 = (tid & 3) * 8;

  for (int kk = 0; kk < 32; ++kk) {
    const int k0 = kk * 32;
    __syncthreads();
    if (A_F32) {
#pragma unroll
      for (int c = 0; c < 2; ++c) {
        const float* p = Af + (size_t)c * 64 * 1024 + k0;
        const float4 f0 = *(const float4*)p;
        const float4 f1 = *(const float4*)(p + 4);
        uint4 u;
        u.x = pk2bf(f0.x, f0.y); u.y = pk2bf(f0.z, f0.w);
        u.z = pk2bf(f1.x, f1.y); u.w = pk2bf(f1.z, f1.w);
        *(uint4*)&As[(arow + c * 64) * AST + ac8] = u;
      }
    } else {
#pragma unroll
      for (int c = 0; c < 2; ++c)
        GLOAD16(Ag16 + (size_t)c * 16 * 1024 + k0, AsB + c * 512);
    }
#pragma unroll
    for (int c = 0; c < 2; ++c)
      GLOAD16(Bg + (size_t)c * 16 * 1024 + k0, BsB + c * 512);
    __syncthreads();

    bfrag a[4], b[4];
#pragma unroll
    for (int m = 0; m < 4; ++m)
      a[m] = __builtin_bit_cast(bfrag, *(const uint4*)&As[(wr * 64 + m * 16 + l15) * AST + g * 8]);
#pragma unroll
    for (int n = 0; n < 4; ++n)
      b[n] = __builtin_bit_cast(bfrag, *(const uint4*)&Bs[(wc * 64 + n * 16 + l15) * 32 + g * 8]);
#pragma unroll
    for (int m = 0; m < 4; ++m)
#pragma unroll
      for (int n = 0; n < 4; ++n)
        acc[m][n] = __builtin_amdgcn_mfma_f32_16x16x32_bf16(a[m], b[n], acc[m][n], 0, 0, 0);
  }

  const int row0 = mb * 128 + wr * 64 + g * 4;
  const int col0 = nb * 128 + wc * 64 + l15;
#pragma unroll
  for (int m = 0; m < 4; ++m) {
#pragma unroll
    for (int n = 0; n < 4; ++n) {
      const int row = row0 + m * 16;
      const int col = col0 + n * 16;
      const float bc = bias[col];
      if (OUT_VT) {
        u16 w[4];
#pragma unroll
        for (int r = 0; r < 4; ++r) w[r] = f2bf(acc[m][n][r] + bc);
        const size_t dst =
            ((size_t)((row >> 11) * 16 + (col >> 6)) * 64 + (col & 63)) * 2048 + (row & 2047);
        *(uint2*)((u16*)Cv + dst) = *(const uint2*)w;
      } else if (OUT_F32) {
#pragma unroll
        for (int r = 0; r < 4; ++r)
          ((float*)Cv)[(size_t)(row + r) * 1024 + col] = acc[m][n][r] + bc;
      } else {
#pragma unroll
        for (int r = 0; r < 4; ++r)
          ((u16*)Cv)[(size_t)(row + r) * 1024 + col] = f2bf(acc[m][n][r] + bc);
      }
    }
  }
}

// ---------------- fused causal flash attention
// Q,K bf16 [B*S,1024]; Vtg bf16 [B*H][64e][2048s] (pre-transposed); O bf16 [B*S,1024].
// 8 waves x 32 q-rows = 256 q-rows/block; KVBLK=64.
__global__ __launch_bounds__(512) void attn_fused(const u16* __restrict__ Qb,
                                                  const u16* __restrict__ Kb,
                                                  const u16* __restrict__ Vtg,
                                                  u16* __restrict__ Ob) {
  __shared__ u16 Ks[64][72];       // [kv][e]
  __shared__ u16 Vs[64][72];       // [e][kv]  (from V^T global)
  __shared__ u16 Pl[8][16][72];    // per-wave P round-trip [q16][kv64]
  const int tid = threadIdx.x;
  const int wid = tid >> 6, lane = tid & 63;
  const int g = lane >> 4, l15 = lane & 15;
  const int b = blockIdx.z, h = blockIdx.y;
  const int qb = (7 - blockIdx.x) * 256;   // big blocks first
  const int q0w = qb + wid * 32;
  const size_t baserow = (size_t)b * 2048;
  const u16* Vg = Vtg + ((size_t)(b * 16 + h) * 64) * 2048;

  bfrag qa[2][2];
#pragma unroll
  for (int qf = 0; qf < 2; ++qf)
#pragma unroll
    for (int kh = 0; kh < 2; ++kh)
      qa[qf][kh] = __builtin_bit_cast(bfrag,
          *(const uint4*)(Qb + (baserow + q0w + qf * 16 + l15) * 1024 + h * 64 + kh * 32 + g * 8));

  f32x4 acc[2][4] = {};
  float M[2][4], L[2][4];
#pragma unroll
  for (int qf = 0; qf < 2; ++qf)
#pragma unroll
    for (int r = 0; r < 4; ++r) { M[qf][r] = -1e30f; L[qf][r] = 0.f; }

  const int krow = tid >> 3, kc8 = (tid & 7) * 8;
  const int nsteps = (qb >> 6) + 4;
  const int sA = (q0w + 31) >> 6;   // wave's diagonal (last active) step

  for (int s = 0; s < nsteps; ++s) {
    const int kv0 = s * 64;
    __syncthreads();
    *(uint4*)&Ks[krow][kc8] = *(const uint4*)(Kb + (baserow + kv0 + krow) * 1024 + h * 64 + kc8);
    *(uint4*)&Vs[krow][kc8] = *(const uint4*)(Vg + (size_t)krow * 2048 + kv0 + kc8);
    __syncthreads();
    if (s > sA) continue;
    const bool full = (s < sA);

#pragma unroll
    for (int qf = 0; qf < 2; ++qf) {
      f32x4 sc[4];
#pragma unroll
      for (int t = 0; t < 4; ++t) {
        const bfrag kb0 = __builtin_bit_cast(bfrag, *(const uint4*)&Ks[t * 16 + l15][g * 8]);
        const bfrag kb1 = __builtin_bit_cast(bfrag, *(const uint4*)&Ks[t * 16 + l15][32 + g * 8]);
        f32x4 z = {0.f, 0.f, 0.f, 0.f};
        z = __builtin_amdgcn_mfma_f32_16x16x32_bf16(qa[qf][0], kb0, z, 0, 0, 0);
        z = __builtin_amdgcn_mfma_f32_16x16x32_bf16(qa[qf][1], kb1, z, 0, 0, 0);
        sc[t] = z;
      }
      if (full) {
#pragma unroll
        for (int t = 0; t < 4; ++t)
#pragma unroll
          for (int r = 0; r < 4; ++r) sc[t][r] *= 0.125f;
      } else {
        const int qrow = q0w + qf * 16 + g * 4;
#pragma unroll
        for (int t = 0; t < 4; ++t) {
          const int kv = kv0 + t * 16 + l15;
#pragma unroll
          for (int r = 0; r < 4; ++r)
            sc[t][r] = (kv <= qrow + r) ? sc[t][r] * 0.125f : -1e30f;
        }
      }
      float mt[4], rs[4], cf[4];
#pragma unroll
      for (int r = 0; r < 4; ++r)
        mt[r] = fmaxf(fmaxf(sc[0][r], sc[1][r]), fmaxf(sc[2][r], sc[3][r]));
#pragma unroll
      for (int off = 1; off < 16; off <<= 1)
#pragma unroll
        for (int r = 0; r < 4; ++r) mt[r] = fmaxf(mt[r], __shfl_xor(mt[r], off));
#pragma unroll
      for (int r = 0; r < 4; ++r) {
        const float Mn = fmaxf(M[qf][r], mt[r]);
        cf[r] = __expf(M[qf][r] - Mn);
        M[qf][r] = Mn;
#pragma unroll
        for (int t = 0; t < 4; ++t) sc[t][r] = __expf(sc[t][r] - Mn);
        rs[r] = (sc[0][r] + sc[1][r]) + (sc[2][r] + sc[3][r]);
      }
#pragma unroll
      for (int off = 1; off < 16; off <<= 1)
#pragma unroll
        for (int r = 0; r < 4; ++r) rs[r] += __shfl_xor(rs[r], off);
#pragma unroll
      for (int r = 0; r < 4; ++r) L[qf][r] = L[qf][r] * cf[r] + rs[r];
#pragma unroll
      for (int et = 0; et < 4; ++et)
#pragma unroll
        for (int r = 0; r < 4; ++r) acc[qf][et][r] *= cf[r];

      // P (C-layout) -> per-wave LDS -> A-operand frags
#pragma unroll
      for (int t = 0; t < 4; ++t)
#pragma unroll
        for (int r = 0; r < 4; ++r)
          Pl[wid][g * 4 + r][t * 16 + l15] = f2bf_ru(sc[t][r]);
#pragma unroll
      for (int kc = 0; kc < 2; ++kc) {
        const bfrag pa = __builtin_bit_cast(bfrag, *(const uint4*)&Pl[wid][l15][kc * 32 + g * 8]);
#pragma unroll
        for (int et = 0; et < 4; ++et) {
          const bfrag vb = __builtin_bit_cast(bfrag, *(const uint4*)&Vs[et * 16 + l15][kc * 32 + g * 8]);
          acc[qf][et] = __builtin_amdgcn_mfma_f32_16x16x32_bf16(pa, vb, acc[qf][et], 0, 0, 0);
        }
      }
    }
  }

#pragma unroll
  for (int qf = 0; qf < 2; ++qf) {
    float inv[4];
#pragma unroll
    for (int r = 0; r < 4; ++r) inv[r] = 1.f / L[qf][r];
#pragma unroll
    for (int et = 0; et < 4; ++et)
#pragma unroll
      for (int r = 0; r < 4; ++r)
        Ob[(baserow + q0w + qf * 16 + g * 4 + r) * 1024 + h * 64 + et * 16 + l15] =
            f2bf(acc[qf][et][r] * inv[r]);
  }
}

extern "C" void kernel_launch(void* const* d_in, const int* in_sizes, int n_in,
                              void* d_out, int out_size, void* d_ws, size_t ws_size,
                              hipStream_t stream) {
  const float* keys    = (const float*)d_in[0];
  const float* queries = (const float*)d_in[1];
  const float* values  = (const float*)d_in[2];
  const float* Wq = (const float*)d_in[3];
  const float* bq = (const float*)d_in[4];
  const float* Wk = (const float*)d_in[5];
  const float* bk = (const float*)d_in[6];
  const float* Wv = (const float*)d_in[7];
  const float* bv = (const float*)d_in[8];
  const float* Wo = (const float*)d_in[9];
  const float* bo = (const float*)d_in[10];
  float* out = (float*)d_out;

  char* ws = (char*)d_ws;
  const size_t MB2 = 1u << 21, MB16 = 1u << 24;
  u16* Wqt = (u16*)(ws + 0 * MB2);
  u16* Wkt = (u16*)(ws + 1 * MB2);
  u16* Wvt = (u16*)(ws + 2 * MB2);
  u16* Wot = (u16*)(ws + 3 * MB2);
  u16* Qb  = (u16*)(ws + 4 * MB2 + 0 * MB16);
  u16* Kb  = (u16*)(ws + 4 * MB2 + 1 * MB16);
  u16* Vtg = (u16*)(ws + 4 * MB2 + 2 * MB16);
  u16* Ob  = (u16*)(ws + 4 * MB2 + 3 * MB16);

  const dim3 pg(16, 16);
  pack_w_hde<<<pg, 256, 0, stream>>>(Wq, Wqt);
  pack_w_hde<<<pg, 256, 0, stream>>>(Wk, Wkt);
  pack_w_hde<<<pg, 256, 0, stream>>>(Wv, Wvt);
  transpose_w<<<pg, 256, 0, stream>>>(Wo, Wot);

  const dim3 gg(8, 64);  // (N/128, M/128)
  gemm128<true, false, false><<<gg, 256, 0, stream>>>(queries, Wqt, bq, Qb);
  gemm128<true, false, false><<<gg, 256, 0, stream>>>(keys,    Wkt, bk, Kb);
  gemm128<true, false, true ><<<gg, 256, 0, stream>>>(values,  Wvt, bv, Vtg);

  attn_fused<<<dim3(8, 16, 4), 512, 0, stream>>>(Qb, Kb, Vtg, Ob);

  gemm128<false, true, false><<<gg, 256, 0, stream>>>(Ob, Wot, bo, out);
}

// Round 3
// 299.200 us; speedup vs baseline: 1.7498x; 1.3287x over previous
//
#include <hip/hip_runtime.h>
#include <stdint.h>

typedef unsigned short u16;
typedef __attribute__((ext_vector_type(4))) float f32x4;
typedef __attribute__((ext_vector_type(8))) short bfrag;

static __device__ __forceinline__ u16 f2bf(float f) {  // RNE
  union { float f; uint32_t u; } v; v.f = f;
  return (u16)((v.u + 0x7fffu + ((v.u >> 16) & 1u)) >> 16);
}
static __device__ __forceinline__ u16 f2bf_ru(float f) {  // round-half-up
  union { float f; uint32_t u; } v; v.f = f;
  return (u16)((v.u + 0x8000u) >> 16);
}
// pack two f32 -> packed bf16x2 (round-half-up) in one v_perm
static __device__ __forceinline__ uint32_t pk2bf(float lo, float hi) {
  union { float f; uint32_t u; } a, b; a.f = lo; b.f = hi;
  return __builtin_amdgcn_perm(b.u + 0x8000u, a.u + 0x8000u, 0x07060302u);
}

#define GLOAD16(gp, lp)                                              \
  __builtin_amdgcn_global_load_lds(                                  \
      (const __attribute__((address_space(1))) uint32_t*)(gp),       \
      (__attribute__((address_space(3))) uint32_t*)(lp), 16, 0, 0)

// ---------------- pack Wq/Wk/Wv: [16][1024][64] f32 -> [1024][1024] bf16
__global__ __launch_bounds__(256) void pack_w_hde(const float* __restrict__ W,
                                                  u16* __restrict__ Wt) {
  __shared__ float tile[64][65];
  const int h = blockIdx.y, k0 = blockIdx.x * 64;
  const int tid = threadIdx.x;
#pragma unroll
  for (int j = 0; j < 4; ++j) {
    int idx = tid + j * 256;
    int rr = idx >> 4, c4 = (idx & 15) * 4;
    const float4 v = *(const float4*)(W + (size_t)h * 65536 + (size_t)(k0 + rr) * 64 + c4);
    tile[rr][c4 + 0] = v.x; tile[rr][c4 + 1] = v.y;
    tile[rr][c4 + 2] = v.z; tile[rr][c4 + 3] = v.w;
  }
  __syncthreads();
#pragma unroll
  for (int j = 0; j < 4; ++j) {
    int idx = tid + j * 256;
    int ee = idx >> 4, c4 = (idx & 15) * 4;
    uint2 u;
    u.x = f2bf(tile[c4 + 0][ee]) | ((uint32_t)f2bf(tile[c4 + 1][ee]) << 16);
    u.y = f2bf(tile[c4 + 2][ee]) | ((uint32_t)f2bf(tile[c4 + 3][ee]) << 16);
    *(uint2*)(Wt + (size_t)(h * 64 + ee) * 1024 + k0 + c4) = u;
  }
}

// ---------------- transpose Wo: [1024][1024] f32 -> bf16, out[n][k] = Wo[k][n]
__global__ __launch_bounds__(256) void transpose_w(const float* __restrict__ W,
                                                   u16* __restrict__ Wt) {
  __shared__ float tile[64][65];
  const int k0 = blockIdx.x * 64, n0 = blockIdx.y * 64;
  const int tid = threadIdx.x;
#pragma unroll
  for (int j = 0; j < 4; ++j) {
    int idx = tid + j * 256;
    int rr = idx >> 4, c4 = (idx & 15) * 4;
    const float4 v = *(const float4*)(W + (size_t)(k0 + rr) * 1024 + n0 + c4);
    tile[rr][c4 + 0] = v.x; tile[rr][c4 + 1] = v.y;
    tile[rr][c4 + 2] = v.z; tile[rr][c4 + 3] = v.w;
  }
  __syncthreads();
#pragma unroll
  for (int j = 0; j < 4; ++j) {
    int idx = tid + j * 256;
    int ee = idx >> 4, c4 = (idx & 15) * 4;
    uint2 u;
    u.x = f2bf(tile[c4 + 0][ee]) | ((uint32_t)f2bf(tile[c4 + 1][ee]) << 16);
    u.y = f2bf(tile[c4 + 2][ee]) | ((uint32_t)f2bf(tile[c4 + 3][ee]) << 16);
    *(uint2*)(Wt + (size_t)(n0 + ee) * 1024 + k0 + c4) = u;
  }
}

// ---------------- GEMM: C[M=8192,N=1024] = A[M,1024]*Bt[n][k]^T + bias[n]
template <bool A_F32, bool OUT_F32, bool OUT_VT>
__global__ __launch_bounds__(256) void gemm128(const void* __restrict__ Av,
                                               const u16* __restrict__ Bt,
                                               const float* __restrict__ bias,
                                               void* __restrict__ Cv) {
  constexpr int AST = A_F32 ? 40 : 32;
  __shared__ u16 As[128 * AST];
  __shared__ u16 Bs[128 * 32];
  const int tid = threadIdx.x;
  const int mb = blockIdx.y, nb = blockIdx.x;
  const int wid = tid >> 6, lane = tid & 63;
  const int wr = wid >> 1, wc = wid & 1;
  const int g = lane >> 4, l15 = lane & 15;
  f32x4 acc[4][4] = {};

  const u16* Bg = Bt + (size_t)(nb * 128 + 2 * wid * 16 + (lane >> 2)) * 1024 + (lane & 3) * 8;
  const u16* Ag16 = (const u16*)Av + (size_t)(mb * 128 + 2 * wid * 16 + (lane >> 2)) * 1024 + (lane & 3) * 8;
  const float* Af = (const float*)Av + (size_t)(mb * 128 + (tid >> 2)) * 1024 + (tid & 3) * 8;
  u16* AsB = &As[2 * wid * 512];
  u16* BsB = &Bs[2 * wid * 512];
  const int arow = tid >> 2, ac8 = (tid & 3) * 8;

  for (int kk = 0; kk < 32; ++kk) {
    const int k0 = kk * 32;
    __syncthreads();
    if (A_F32) {
#pragma unroll
      for (int c = 0; c < 2; ++c) {
        const float* p = Af + (size_t)c * 64 * 1024 + k0;
        const float4 f0 = *(const float4*)p;
        const float4 f1 = *(const float4*)(p + 4);
        uint4 u;
        u.x = pk2bf(f0.x, f0.y); u.y = pk2bf(f0.z, f0.w);
        u.z = pk2bf(f1.x, f1.y); u.w = pk2bf(f1.z, f1.w);
        *(uint4*)&As[(arow + c * 64) * AST + ac8] = u;
      }
    } else {
#pragma unroll
      for (int c = 0; c < 2; ++c)
        GLOAD16(Ag16 + (size_t)c * 16 * 1024 + k0, AsB + c * 512);
    }
#pragma unroll
    for (int c = 0; c < 2; ++c)
      GLOAD16(Bg + (size_t)c * 16 * 1024 + k0, BsB + c * 512);
    __syncthreads();

    bfrag a[4], b[4];
#pragma unroll
    for (int m = 0; m < 4; ++m)
      a[m] = __builtin_bit_cast(bfrag, *(const uint4*)&As[(wr * 64 + m * 16 + l15) * AST + g * 8]);
#pragma unroll
    for (int n = 0; n < 4; ++n)
      b[n] = __builtin_bit_cast(bfrag, *(const uint4*)&Bs[(wc * 64 + n * 16 + l15) * 32 + g * 8]);
    __builtin_amdgcn_s_setprio(1);
#pragma unroll
    for (int m = 0; m < 4; ++m)
#pragma unroll
      for (int n = 0; n < 4; ++n)
        acc[m][n] = __builtin_amdgcn_mfma_f32_16x16x32_bf16(a[m], b[n], acc[m][n], 0, 0, 0);
    __builtin_amdgcn_s_setprio(0);
  }

  const int row0 = mb * 128 + wr * 64 + g * 4;
  const int col0 = nb * 128 + wc * 64 + l15;
#pragma unroll
  for (int m = 0; m < 4; ++m) {
#pragma unroll
    for (int n = 0; n < 4; ++n) {
      const int row = row0 + m * 16;
      const int col = col0 + n * 16;
      const float bc = bias[col];
      if (OUT_VT) {
        u16 w[4];
#pragma unroll
        for (int r = 0; r < 4; ++r) w[r] = f2bf(acc[m][n][r] + bc);
        const size_t dst =
            ((size_t)((row >> 11) * 16 + (col >> 6)) * 64 + (col & 63)) * 2048 + (row & 2047);
        *(uint2*)((u16*)Cv + dst) = *(const uint2*)w;
      } else if (OUT_F32) {
#pragma unroll
        for (int r = 0; r < 4; ++r)
          ((float*)Cv)[(size_t)(row + r) * 1024 + col] = acc[m][n][r] + bc;
      } else {
#pragma unroll
        for (int r = 0; r < 4; ++r)
          ((u16*)Cv)[(size_t)(row + r) * 1024 + col] = f2bf(acc[m][n][r] + bc);
      }
    }
  }
}

// ---------------- fused causal flash attention, wave-independent, no barriers
// Q,K bf16 [B*S,1024]; Vtg bf16 [B*H][64e][2048s]; O bf16 [B*S,1024].
// 4 waves/block; wave handles q-tiles u and 63-u (32 rows each) -> 33 KV steps
// uniform. K/V fragments loaded directly from global (L2-resident panels).
__global__ __launch_bounds__(256) void attn_fused(const u16* __restrict__ Qb,
                                                  const u16* __restrict__ Kb,
                                                  const u16* __restrict__ Vtg,
                                                  u16* __restrict__ Ob) {
  __shared__ u16 Pp[4][16][72];
  const int tid = threadIdx.x;
  const int wid = tid >> 6, lane = tid & 63;
  const int g = lane >> 4, l15 = lane & 15;

  // XCD swizzle: 512 blocks, xcd = n&7 owns bh in {8*xcd .. 8*xcd+7}
  const int n = blockIdx.x;
  const int xcd = n & 7, m = n >> 3;
  const int bh = xcd * 8 + (m & 7);
  const int xb = m >> 3;                 // 0..7
  const int b = bh >> 4, h = bh & 15;
  const int u = xb * 4 + wid;            // pair unit 0..31
  const size_t baserow = (size_t)b * 2048;
  const u16* Qg = Qb + baserow * 1024 + h * 64;
  const u16* Kg = Kb + baserow * 1024 + h * 64;
  const u16* Vg = Vtg + (size_t)bh * 64 * 2048;
  u16* Og = Ob + baserow * 1024 + h * 64;

  auto run_tile = [&](int q0) {
    bfrag qa[2][2];
#pragma unroll
    for (int qf = 0; qf < 2; ++qf)
#pragma unroll
      for (int kh = 0; kh < 2; ++kh)
        qa[qf][kh] = __builtin_bit_cast(bfrag,
            *(const uint4*)(Qg + (size_t)(q0 + qf * 16 + l15) * 1024 + kh * 32 + g * 8));

    f32x4 acc[2][4] = {};
    float M[2][4], L[2][4];
#pragma unroll
    for (int qf = 0; qf < 2; ++qf)
#pragma unroll
      for (int r = 0; r < 4; ++r) { M[qf][r] = -1e30f; L[qf][r] = 0.f; }

    const int nsteps = (q0 >> 6) + 1;
    for (int s = 0; s < nsteps; ++s) {
      const int kv0 = s << 6;
      const bool diag = (s == nsteps - 1);

      bfrag kb[2][4];
#pragma unroll
      for (int t = 0; t < 4; ++t)
#pragma unroll
        for (int kh = 0; kh < 2; ++kh)
          kb[kh][t] = __builtin_bit_cast(bfrag,
              *(const uint4*)(Kg + (size_t)(kv0 + t * 16 + l15) * 1024 + kh * 32 + g * 8));

      f32x4 sc[2][4];
      __builtin_amdgcn_s_setprio(1);
#pragma unroll
      for (int qf = 0; qf < 2; ++qf)
#pragma unroll
        for (int t = 0; t < 4; ++t) {
          f32x4 z = {0.f, 0.f, 0.f, 0.f};
          z = __builtin_amdgcn_mfma_f32_16x16x32_bf16(qa[qf][0], kb[0][t], z, 0, 0, 0);
          z = __builtin_amdgcn_mfma_f32_16x16x32_bf16(qa[qf][1], kb[1][t], z, 0, 0, 0);
          sc[qf][t] = z;
        }
      __builtin_amdgcn_s_setprio(0);

      // V fragments (kb now dead); in flight across the softmax
      bfrag vb[2][4];
#pragma unroll
      for (int et = 0; et < 4; ++et)
#pragma unroll
        for (int kc = 0; kc < 2; ++kc)
          vb[kc][et] = __builtin_bit_cast(bfrag,
              *(const uint4*)(Vg + (size_t)(et * 16 + l15) * 2048 + kv0 + kc * 32 + g * 8));

#pragma unroll
      for (int qf = 0; qf < 2; ++qf) {
        if (!diag) {
#pragma unroll
          for (int t = 0; t < 4; ++t)
#pragma unroll
            for (int r = 0; r < 4; ++r) sc[qf][t][r] *= 0.125f;
        } else {
          const int qrow = q0 + qf * 16 + g * 4;
#pragma unroll
          for (int t = 0; t < 4; ++t) {
            const int kv = kv0 + t * 16 + l15;
#pragma unroll
            for (int r = 0; r < 4; ++r)
              sc[qf][t][r] = (kv <= qrow + r) ? sc[qf][t][r] * 0.125f : -1e30f;
          }
        }
        float mt[4], rs[4], cf[4];
#pragma unroll
        for (int r = 0; r < 4; ++r)
          mt[r] = fmaxf(fmaxf(sc[qf][0][r], sc[qf][1][r]), fmaxf(sc[qf][2][r], sc[qf][3][r]));
#pragma unroll
        for (int off = 1; off < 16; off <<= 1)
#pragma unroll
          for (int r = 0; r < 4; ++r) mt[r] = fmaxf(mt[r], __shfl_xor(mt[r], off));
#pragma unroll
        for (int r = 0; r < 4; ++r) {
          const float Mn = fmaxf(M[qf][r], mt[r]);
          cf[r] = __expf(M[qf][r] - Mn);
          M[qf][r] = Mn;
#pragma unroll
          for (int t = 0; t < 4; ++t) sc[qf][t][r] = __expf(sc[qf][t][r] - Mn);
          rs[r] = (sc[qf][0][r] + sc[qf][1][r]) + (sc[qf][2][r] + sc[qf][3][r]);
        }
#pragma unroll
        for (int off = 1; off < 16; off <<= 1)
#pragma unroll
          for (int r = 0; r < 4; ++r) rs[r] += __shfl_xor(rs[r], off);
#pragma unroll
        for (int r = 0; r < 4; ++r) L[qf][r] = L[qf][r] * cf[r] + rs[r];
#pragma unroll
        for (int et = 0; et < 4; ++et)
#pragma unroll
          for (int r = 0; r < 4; ++r) acc[qf][et][r] *= cf[r];

        // P (C-layout) -> per-wave LDS -> A-operand frags
#pragma unroll
        for (int t = 0; t < 4; ++t)
#pragma unroll
          for (int r = 0; r < 4; ++r)
            Pp[wid][g * 4 + r][t * 16 + l15] = f2bf_ru(sc[qf][t][r]);
        __builtin_amdgcn_s_setprio(1);
#pragma unroll
        for (int kc = 0; kc < 2; ++kc) {
          const bfrag pa = __builtin_bit_cast(bfrag, *(const uint4*)&Pp[wid][l15][kc * 32 + g * 8]);
#pragma unroll
          for (int et = 0; et < 4; ++et)
            acc[qf][et] = __builtin_amdgcn_mfma_f32_16x16x32_bf16(pa, vb[kc][et], acc[qf][et], 0, 0, 0);
        }
        __builtin_amdgcn_s_setprio(0);
      }
    }

#pragma unroll
    for (int qf = 0; qf < 2; ++qf) {
      float inv[4];
#pragma unroll
      for (int r = 0; r < 4; ++r) inv[r] = 1.f / L[qf][r];
#pragma unroll
      for (int et = 0; et < 4; ++et)
#pragma unroll
        for (int r = 0; r < 4; ++r)
          Og[(size_t)(q0 + qf * 16 + g * 4 + r) * 1024 + et * 16 + l15] =
              f2bf(acc[qf][et][r] * inv[r]);
    }
  };

  run_tile(u * 32);
  run_tile((63 - u) * 32);
}

extern "C" void kernel_launch(void* const* d_in, const int* in_sizes, int n_in,
                              void* d_out, int out_size, void* d_ws, size_t ws_size,
                              hipStream_t stream) {
  const float* keys    = (const float*)d_in[0];
  const float* queries = (const float*)d_in[1];
  const float* values  = (const float*)d_in[2];
  const float* Wq = (const float*)d_in[3];
  const float* bq = (const float*)d_in[4];
  const float* Wk = (const float*)d_in[5];
  const float* bk = (const float*)d_in[6];
  const float* Wv = (const float*)d_in[7];
  const float* bv = (const float*)d_in[8];
  const float* Wo = (const float*)d_in[9];
  const float* bo = (const float*)d_in[10];
  float* out = (float*)d_out;

  char* ws = (char*)d_ws;
  const size_t MB2 = 1u << 21, MB16 = 1u << 24;
  u16* Wqt = (u16*)(ws + 0 * MB2);
  u16* Wkt = (u16*)(ws + 1 * MB2);
  u16* Wvt = (u16*)(ws + 2 * MB2);
  u16* Wot = (u16*)(ws + 3 * MB2);
  u16* Qb  = (u16*)(ws + 4 * MB2 + 0 * MB16);
  u16* Kb  = (u16*)(ws + 4 * MB2 + 1 * MB16);
  u16* Vtg = (u16*)(ws + 4 * MB2 + 2 * MB16);
  u16* Ob  = (u16*)(ws + 4 * MB2 + 3 * MB16);

  const dim3 pg(16, 16);
  pack_w_hde<<<pg, 256, 0, stream>>>(Wq, Wqt);
  pack_w_hde<<<pg, 256, 0, stream>>>(Wk, Wkt);
  pack_w_hde<<<pg, 256, 0, stream>>>(Wv, Wvt);
  transpose_w<<<pg, 256, 0, stream>>>(Wo, Wot);

  const dim3 gg(8, 64);  // (N/128, M/128)
  gemm128<true, false, false><<<gg, 256, 0, stream>>>(queries, Wqt, bq, Qb);
  gemm128<true, false, false><<<gg, 256, 0, stream>>>(keys,    Wkt, bk, Kb);
  gemm128<true, false, true ><<<gg, 256, 0, stream>>>(values,  Wvt, bv, Vtg);

  attn_fused<<<dim3(512), 256, 0, stream>>>(Qb, Kb, Vtg, Ob);

  gemm128<false, true, false><<<gg, 256, 0, stream>>>(Ob, Wot, bo, out);
}